// Round 17
// baseline (308.281 us; speedup 1.0000x reference)
//
#include <hip/hip_runtime.h>

#define N_NODES 100000
#define N_EDGES 1600000
#define D 128

#define NSLOT   72    // ints per node region (288B, 16B-aligned); [0]=cnt, [4..71]=srcs
#define CAP     68
#define OVF_MAX 4096

typedef unsigned short ushort_t;
struct ushort4_t { ushort_t x, y, z, w; };
typedef __attribute__((ext_vector_type(8))) short bf16x8;
typedef __attribute__((ext_vector_type(4))) float f32x4;
typedef float vf4 __attribute__((ext_vector_type(4)));

#define NB_EDGE (N_EDGES / 256)           // 6250
#define NB_WBF  16
#define NB_LN   (N_NODES / 8)             // 12500

__device__ __forceinline__ ushort_t f2bf(float f) {
    unsigned u = __float_as_uint(f);
    unsigned r = (u + 0x7fffu + ((u >> 16) & 1u)) >> 16;   // RNE
    return (ushort_t)r;
}
__device__ __forceinline__ float bf2f(ushort_t b) {
    return __uint_as_float(((unsigned)b) << 16);
}

// ---------------- K1: bucket scatter (inline cnt) | wbf | LayerNorm+ReLU ---------
// pos = atomicAdd(&bucket[d*72]); dependent src store hits the SAME hot line.
// (r13 config — measured 233.8 us total; NT variants regressed, reverted.)
__global__ __launch_bounds__(256) void build_wbf_ln_kernel(
    const void* __restrict__ e_raw, int* __restrict__ bucket,
    int* __restrict__ ovf, int* __restrict__ ovf_cnt,
    const float* __restrict__ W, ushort_t* __restrict__ wbf,
    const float* __restrict__ x, const float* __restrict__ gamma,
    const float* __restrict__ beta, ushort_t* __restrict__ hb)
{
    int b = blockIdx.x;
    if (b < NB_EDGE) {
        // inline int64-vs-int32 detect: odd int32 words of first 64 entries all 0
        int li = threadIdx.x & 63;
        int probe = ((const int*)e_raw)[2 * li + 1];
        bool is64 = (__ballot(probe == 0) == ~0ULL);   // wave-uniform

        int e = b * 256 + threadIdx.x;                 // exactly N_EDGES threads
        int s, d;
        if (is64) {
            s = (int)__builtin_nontemporal_load(&((const long long*)e_raw)[e]);
            d = (int)__builtin_nontemporal_load(&((const long long*)e_raw)[N_EDGES + e]);
        } else {
            s = __builtin_nontemporal_load(&((const int*)e_raw)[e]);
            d = __builtin_nontemporal_load(&((const int*)e_raw)[N_EDGES + e]);
        }
        int* reg = bucket + (size_t)d * NSLOT;
        int pos = atomicAdd(reg, 1);
        if (pos < CAP) {
            reg[4 + pos] = s;                          // same hot line as the atomic
        } else {
            int op = atomicAdd(ovf_cnt, 1);            // essentially never
            if (op < OVF_MAX) { ovf[op * 2] = d; ovf[op * 2 + 1] = s; }
        }
    } else if (b < NB_EDGE + NB_WBF) {
        // wbf: W -> bf16, 16 blocks cover 128*128
        int i = ((b - NB_EDGE) * 256 + threadIdx.x) * 4;
        float4 w = *(const float4*)(W + i);
        ushort4_t o;
        o.x = f2bf(w.x); o.y = f2bf(w.y); o.z = f2bf(w.z); o.w = f2bf(w.w);
        *(ushort4_t*)(wbf + i) = o;
    } else {
        int wave   = threadIdx.x >> 6;
        int half   = (threadIdx.x >> 5) & 1;
        int lane32 = threadIdx.x & 31;
        int row = (b - NB_EDGE - NB_WBF) * 8 + wave * 2 + half;
        float4 v = ((const float4*)(x + (size_t)row * D))[lane32];
        float s  = (v.x + v.y) + (v.z + v.w);
        float sq = (v.x * v.x + v.y * v.y) + (v.z * v.z + v.w * v.w);
#pragma unroll
        for (int m = 16; m >= 1; m >>= 1) {
            s  += __shfl_xor(s, m);
            sq += __shfl_xor(sq, m);
        }
        float mu   = s * (1.0f / D);
        float var  = sq * (1.0f / D) - mu * mu;
        float rstd = rsqrtf(var + 1e-5f);
        float4 g = ((const float4*)gamma)[lane32];
        float4 bb = ((const float4*)beta)[lane32];
        ushort4_t o;
        o.x = f2bf(fmaxf(fmaf((v.x - mu) * rstd, g.x, bb.x), 0.0f));
        o.y = f2bf(fmaxf(fmaf((v.y - mu) * rstd, g.y, bb.y), 0.0f));
        o.z = f2bf(fmaxf(fmaf((v.z - mu) * rstd, g.z, bb.z), 0.0f));
        o.w = f2bf(fmaxf(fmaf((v.w - mu) * rstd, g.w, bb.w), 0.0f));
        *(ushort4_t*)(hb + (size_t)row * D + lane32 * 4) = o;
    }
}

// ---------------- K2: fused segsum + GEMM ----------------------------------------
// Block = 64 nodes, 4 waves. Phase 1: wave wv segsums nodes wv*16+j (j=0..15),
// t = bf16(ep1*h + aggr) packed to LDS rows (stride 68 dwords: 16B-aligned b128
// reads, 2-way bank aliasing = free). Phase 2: wave reads only its OWN rows
// (no barrier) and runs the swapped-MFMA GEMM + float4 epilogue. aggrb is gone.
__global__ __launch_bounds__(256) void seg_gemm_kernel(
    const ushort_t* __restrict__ hb, const int* __restrict__ bucket,
    const int* __restrict__ ovf, const int* __restrict__ ovf_cnt,
    const float* __restrict__ x, const ushort_t* __restrict__ wbf,
    const float* __restrict__ bias, const float* __restrict__ eps_p,
    float* __restrict__ out)
{
    __shared__ unsigned t_lds[64 * 68];           // 17.4 KB
    const int wv   = threadIdx.x >> 6;
    const int lane = threadIdx.x & 63;
    const int l16  = lane & 15;
    const int kg   = lane >> 4;                   // 0..3
    const int node0 = blockIdx.x * 64;
    const float ep1 = 1.0f + eps_p[0];
    const unsigned* hrow = (const unsigned*)hb;   // 64 dwords per node row

    int oc = *ovf_cnt;
    oc = oc < OVF_MAX ? oc : OVF_MAX;

    // ---- phase 1: segsum for this wave's 16 nodes -> t rows in LDS ----
    for (int j = 0; j < 16; ++j) {
        int n = node0 + wv * 16 + j;
        float ax = 0.0f, ay = 0.0f;
        if (n < N_NODES) {
            const int* reg = bucket + (size_t)n * NSLOT;
            int deg  = reg[0];
            int eend = deg < CAP ? deg : CAP;
            const int* seg = reg + 4;
            int e = 0;
            for (; e + 8 <= eend; e += 8) {
                int4 sa = *(const int4*)(seg + e);
                int4 sb = *(const int4*)(seg + e + 4);
                unsigned p0 = hrow[(size_t)sa.x * 64 + lane];
                unsigned p1 = hrow[(size_t)sa.y * 64 + lane];
                unsigned p2 = hrow[(size_t)sa.z * 64 + lane];
                unsigned p3 = hrow[(size_t)sa.w * 64 + lane];
                unsigned p4 = hrow[(size_t)sb.x * 64 + lane];
                unsigned p5 = hrow[(size_t)sb.y * 64 + lane];
                unsigned p6 = hrow[(size_t)sb.z * 64 + lane];
                unsigned p7 = hrow[(size_t)sb.w * 64 + lane];
                ax += bf2f((ushort_t)(p0 & 0xffffu)) + bf2f((ushort_t)(p1 & 0xffffu))
                    + bf2f((ushort_t)(p2 & 0xffffu)) + bf2f((ushort_t)(p3 & 0xffffu))
                    + bf2f((ushort_t)(p4 & 0xffffu)) + bf2f((ushort_t)(p5 & 0xffffu))
                    + bf2f((ushort_t)(p6 & 0xffffu)) + bf2f((ushort_t)(p7 & 0xffffu));
                ay += bf2f((ushort_t)(p0 >> 16)) + bf2f((ushort_t)(p1 >> 16))
                    + bf2f((ushort_t)(p2 >> 16)) + bf2f((ushort_t)(p3 >> 16))
                    + bf2f((ushort_t)(p4 >> 16)) + bf2f((ushort_t)(p5 >> 16))
                    + bf2f((ushort_t)(p6 >> 16)) + bf2f((ushort_t)(p7 >> 16));
            }
            for (; e < eend; ++e) {
                int s = seg[e];
                unsigned p = hrow[(size_t)s * 64 + lane];
                ax += bf2f((ushort_t)(p & 0xffffu));
                ay += bf2f((ushort_t)(p >> 16));
            }
            if (oc > 0) {                          // overflow entries (~0)
                for (int i = 0; i < oc; ++i) {
                    if (ovf[2 * i] == n) {
                        unsigned p = hrow[(size_t)ovf[2 * i + 1] * 64 + lane];
                        ax += bf2f((ushort_t)(p & 0xffffu));
                        ay += bf2f((ushort_t)(p >> 16));
                    }
                }
            }
            // fold own h row: t = ep1*h + aggr
            unsigned hp = hrow[(size_t)n * 64 + lane];
            ax = fmaf(ep1, bf2f((ushort_t)(hp & 0xffffu)), ax);
            ay = fmaf(ep1, bf2f((ushort_t)(hp >> 16)), ay);
        }
        t_lds[(wv * 16 + j) * 68 + lane] =
            (unsigned)f2bf(ax) | ((unsigned)f2bf(ay) << 16);
    }

    // ---- phase 2: GEMM from LDS (own rows only; no barrier needed) ----
    f32x4 acc[8];
#pragma unroll
    for (int nt = 0; nt < 8; ++nt) acc[nt] = (f32x4){0.f, 0.f, 0.f, 0.f};

#pragma unroll
    for (int ks = 0; ks < 4; ++ks) {
        const int k0 = ks * 32 + kg * 8;
        bf16x8 af = *(const bf16x8*)&t_lds[(wv * 16 + l16) * 68 + ks * 16 + kg * 4];
#pragma unroll
        for (int nt = 0; nt < 8; ++nt) {
            bf16x8 bf = *(const bf16x8*)(wbf + (size_t)(nt * 16 + l16) * D + k0);
            acc[nt] = __builtin_amdgcn_mfma_f32_16x16x32_bf16(bf, af, acc[nt], 0, 0, 0);
        }
    }

    // epilogue: lane (l16,kg) holds node row l16, cols nt*16 + kg*4 + (0..3)
    int node = node0 + wv * 16 + l16;
    if (node < N_NODES) {
#pragma unroll
        for (int nt = 0; nt < 8; ++nt) {
            int c0 = nt * 16 + kg * 4;
            float4 bv = *(const float4*)(bias + c0);
            vf4 xv = __builtin_nontemporal_load((const vf4*)(x + (size_t)node * D + c0));
            vf4 o;
            o.x = acc[nt][0] + bv.x + xv.x;
            o.y = acc[nt][1] + bv.y + xv.y;
            o.z = acc[nt][2] + bv.z + xv.z;
            o.w = acc[nt][3] + bv.w + xv.w;
            __builtin_nontemporal_store(o, (vf4*)(out + (size_t)node * D + c0));
        }
    }
}

extern "C" void kernel_launch(void* const* d_in, const int* in_sizes, int n_in,
                              void* d_out, int out_size, void* d_ws, size_t ws_size,
                              hipStream_t stream)
{
    const float* x     = (const float*)d_in[0];
    const void*  ei    = d_in[1];
    const float* gamma = (const float*)d_in[2];
    const float* beta  = (const float*)d_in[3];
    const float* W     = (const float*)d_in[4];
    const float* bias  = (const float*)d_in[5];
    const float* eps_p = (const float*)d_in[6];
    float* out = (float*)d_out;

    char* ws = (char*)d_ws;
    size_t off = 0;
    ushort_t* hb      = (ushort_t*)(ws + off); off += (size_t)N_NODES * D * 2;       // 25.6 MB
    int*      bucket  = (int*)(ws + off);      off += (size_t)N_NODES * NSLOT * 4;   // 28.8 MB
    ushort_t* wbf     = (ushort_t*)(ws + off); off += (size_t)D * D * 2;             //  32 KB
    int*      ovf     = (int*)(ws + off);      off += (size_t)OVF_MAX * 2 * 4;       //  32 KB
    int*      ovf_cnt = (int*)(ws + off);      off += 4;

    (void)hipMemsetAsync(bucket, 0, (size_t)N_NODES * NSLOT * 4, stream);  // zero cnts
    (void)hipMemsetAsync(ovf_cnt, 0, 4, stream);
    build_wbf_ln_kernel<<<NB_EDGE + NB_WBF + NB_LN, 256, 0, stream>>>(
        ei, bucket, ovf, ovf_cnt, W, wbf, x, gamma, beta, hb);
    seg_gemm_kernel<<<(N_NODES + 63) / 64, 256, 0, stream>>>(
        hb, bucket, ovf, ovf_cnt, x, wbf, bias, eps_p, out);
}

// Round 18
// 233.174 us; speedup vs baseline: 1.3221x; 1.3221x over previous
//
#include <hip/hip_runtime.h>

#define N_NODES 100000
#define N_EDGES 1600000
#define D 128

#define NSLOT   72    // ints per node region (288B, 16B-aligned); [0]=cnt, [4..71]=srcs
#define CAP     68
#define OVF_MAX 4096

typedef unsigned short ushort_t;
struct ushort4_t { ushort_t x, y, z, w; };
typedef __attribute__((ext_vector_type(8))) short bf16x8;
typedef __attribute__((ext_vector_type(4))) float f32x4;
typedef float vf4 __attribute__((ext_vector_type(4)));

#define NB_EDGE (N_EDGES / 256)           // 6250
#define NB_WBF  16
#define NB_LN   (N_NODES / 8)             // 12500

__device__ __forceinline__ ushort_t f2bf(float f) {
    unsigned u = __float_as_uint(f);
    unsigned r = (u + 0x7fffu + ((u >> 16) & 1u)) >> 16;   // RNE
    return (ushort_t)r;
}
__device__ __forceinline__ float bf2f(ushort_t b) {
    return __uint_as_float(((unsigned)b) << 16);
}

// ---------------- K1: bucket scatter (inline cnt) | wbf | LayerNorm+ReLU ---------
// pos = atomicAdd(&bucket[d*72]); dependent src store hits the SAME hot line.
// (r13/r14 config — fastest measured; NT variants regressed.)
__global__ __launch_bounds__(256) void build_wbf_ln_kernel(
    const void* __restrict__ e_raw, int* __restrict__ bucket,
    int* __restrict__ ovf, int* __restrict__ ovf_cnt,
    const float* __restrict__ W, ushort_t* __restrict__ wbf,
    const float* __restrict__ x, const float* __restrict__ gamma,
    const float* __restrict__ beta, ushort_t* __restrict__ hb)
{
    int b = blockIdx.x;
    if (b < NB_EDGE) {
        // inline int64-vs-int32 detect: odd int32 words of first 64 entries all 0
        int li = threadIdx.x & 63;
        int probe = ((const int*)e_raw)[2 * li + 1];
        bool is64 = (__ballot(probe == 0) == ~0ULL);   // wave-uniform

        int e = b * 256 + threadIdx.x;                 // exactly N_EDGES threads
        int s, d;
        if (is64) {
            s = (int)__builtin_nontemporal_load(&((const long long*)e_raw)[e]);
            d = (int)__builtin_nontemporal_load(&((const long long*)e_raw)[N_EDGES + e]);
        } else {
            s = __builtin_nontemporal_load(&((const int*)e_raw)[e]);
            d = __builtin_nontemporal_load(&((const int*)e_raw)[N_EDGES + e]);
        }
        int* reg = bucket + (size_t)d * NSLOT;
        int pos = atomicAdd(reg, 1);
        if (pos < CAP) {
            reg[4 + pos] = s;                          // same hot line as the atomic
        } else {
            int op = atomicAdd(ovf_cnt, 1);            // essentially never
            if (op < OVF_MAX) { ovf[op * 2] = d; ovf[op * 2 + 1] = s; }
        }
    } else if (b < NB_EDGE + NB_WBF) {
        // wbf: W -> bf16, 16 blocks cover 128*128
        int i = ((b - NB_EDGE) * 256 + threadIdx.x) * 4;
        float4 w = *(const float4*)(W + i);
        ushort4_t o;
        o.x = f2bf(w.x); o.y = f2bf(w.y); o.z = f2bf(w.z); o.w = f2bf(w.w);
        *(ushort4_t*)(wbf + i) = o;
    } else {
        int wave   = threadIdx.x >> 6;
        int half   = (threadIdx.x >> 5) & 1;
        int lane32 = threadIdx.x & 31;
        int row = (b - NB_EDGE - NB_WBF) * 8 + wave * 2 + half;
        float4 v = ((const float4*)(x + (size_t)row * D))[lane32];
        float s  = (v.x + v.y) + (v.z + v.w);
        float sq = (v.x * v.x + v.y * v.y) + (v.z * v.z + v.w * v.w);
#pragma unroll
        for (int m = 16; m >= 1; m >>= 1) {
            s  += __shfl_xor(s, m);
            sq += __shfl_xor(sq, m);
        }
        float mu   = s * (1.0f / D);
        float var  = sq * (1.0f / D) - mu * mu;
        float rstd = rsqrtf(var + 1e-5f);
        float4 g = ((const float4*)gamma)[lane32];
        float4 bb = ((const float4*)beta)[lane32];
        ushort4_t o;
        o.x = f2bf(fmaxf(fmaf((v.x - mu) * rstd, g.x, bb.x), 0.0f));
        o.y = f2bf(fmaxf(fmaf((v.y - mu) * rstd, g.y, bb.y), 0.0f));
        o.z = f2bf(fmaxf(fmaf((v.z - mu) * rstd, g.z, bb.z), 0.0f));
        o.w = f2bf(fmaxf(fmaf((v.w - mu) * rstd, g.w, bb.w), 0.0f));
        *(ushort4_t*)(hb + (size_t)row * D + lane32 * 4) = o;
    }
}

// ---------------- K2: bucket segment sum + t-fold — one wave per node ------------
// Emits t = bf16(ep1*h[n] + sum(h[src])) directly (the GEMM A-operand), so the
// GEMM reads only tb (25.6 MB) instead of hb+aggrb (51 MB).
__global__ __launch_bounds__(256) void bucket_segsum_kernel(
    const ushort_t* __restrict__ hb, const int* __restrict__ bucket,
    const int* __restrict__ ovf, const int* __restrict__ ovf_cnt,
    const float* __restrict__ eps_p, ushort_t* __restrict__ tb)
{
    int n    = blockIdx.x * 4 + (threadIdx.x >> 6);
    int lane = threadIdx.x & 63;
    const int* reg = bucket + (size_t)n * NSLOT;
    int deg  = reg[0];
    int eend = deg < CAP ? deg : CAP;
    const int* seg = reg + 4;
    const unsigned* hrow = (const unsigned*)hb;   // 64 dwords per node row
    float ax = 0.0f, ay = 0.0f;
    int e = 0;

    for (; e + 8 <= eend; e += 8) {
        int4 sa = *(const int4*)(seg + e);
        int4 sb = *(const int4*)(seg + e + 4);
        unsigned p0 = hrow[(size_t)sa.x * 64 + lane];
        unsigned p1 = hrow[(size_t)sa.y * 64 + lane];
        unsigned p2 = hrow[(size_t)sa.z * 64 + lane];
        unsigned p3 = hrow[(size_t)sa.w * 64 + lane];
        unsigned p4 = hrow[(size_t)sb.x * 64 + lane];
        unsigned p5 = hrow[(size_t)sb.y * 64 + lane];
        unsigned p6 = hrow[(size_t)sb.z * 64 + lane];
        unsigned p7 = hrow[(size_t)sb.w * 64 + lane];
        ax += bf2f((ushort_t)(p0 & 0xffffu)) + bf2f((ushort_t)(p1 & 0xffffu))
            + bf2f((ushort_t)(p2 & 0xffffu)) + bf2f((ushort_t)(p3 & 0xffffu))
            + bf2f((ushort_t)(p4 & 0xffffu)) + bf2f((ushort_t)(p5 & 0xffffu))
            + bf2f((ushort_t)(p6 & 0xffffu)) + bf2f((ushort_t)(p7 & 0xffffu));
        ay += bf2f((ushort_t)(p0 >> 16)) + bf2f((ushort_t)(p1 >> 16))
            + bf2f((ushort_t)(p2 >> 16)) + bf2f((ushort_t)(p3 >> 16))
            + bf2f((ushort_t)(p4 >> 16)) + bf2f((ushort_t)(p5 >> 16))
            + bf2f((ushort_t)(p6 >> 16)) + bf2f((ushort_t)(p7 >> 16));
    }
    for (; e < eend; ++e) {
        int s = seg[e];
        unsigned p = hrow[(size_t)s * 64 + lane];
        ax += bf2f((ushort_t)(p & 0xffffu));
        ay += bf2f((ushort_t)(p >> 16));
    }

    // overflow entries (count ~0; wave-uniform branch)
    int oc = *ovf_cnt;
    if (oc > 0) {
        oc = oc < OVF_MAX ? oc : OVF_MAX;
        for (int i = 0; i < oc; ++i) {
            if (ovf[2 * i] == n) {
                unsigned p = hrow[(size_t)ovf[2 * i + 1] * 64 + lane];
                ax += bf2f((ushort_t)(p & 0xffffu));
                ay += bf2f((ushort_t)(p >> 16));
            }
        }
    }

    // fold own h row: t = ep1*h + aggr
    float ep1 = 1.0f + eps_p[0];
    unsigned hp = hrow[(size_t)n * 64 + lane];
    ax = fmaf(ep1, bf2f((ushort_t)(hp & 0xffffu)), ax);
    ay = fmaf(ep1, bf2f((ushort_t)(hp >> 16)), ay);

    unsigned o = (unsigned)f2bf(ax) | ((unsigned)f2bf(ay) << 16);
    __builtin_nontemporal_store(o, (unsigned*)tb + (size_t)n * 64 + lane);
}

// ---------------- K3: out = t @ W^T + b + x  (MFMA, swapped operands) ------------
// A-operand = precomputed t (bf16). lane (l16,kg) -> node row l16,
// cols nt*16 + kg*4 + (0..3); float4 epilogue.
__global__ __launch_bounds__(256) void gemm_mfma_kernel(
    const ushort_t* __restrict__ tb, const float* __restrict__ x,
    const ushort_t* __restrict__ wbf, const float* __restrict__ bias,
    float* __restrict__ out)
{
    const int wv   = threadIdx.x >> 6;
    const int lane = threadIdx.x & 63;
    const int l16  = lane & 15;
    const int kg   = lane >> 4;                 // 0..3
    const int node = blockIdx.x * 64 + wv * 16 + l16;
    const int rowc = node < N_NODES ? node : N_NODES - 1;

    f32x4 acc[8];
#pragma unroll
    for (int nt = 0; nt < 8; ++nt) acc[nt] = (f32x4){0.f, 0.f, 0.f, 0.f};

#pragma unroll
    for (int ks = 0; ks < 4; ++ks) {
        const int k0 = ks * 32 + kg * 8;
        bf16x8 af = *(const bf16x8*)(tb + (size_t)rowc * D + k0);
#pragma unroll
        for (int nt = 0; nt < 8; ++nt) {
            bf16x8 bf = *(const bf16x8*)(wbf + (size_t)(nt * 16 + l16) * D + k0);
            acc[nt] = __builtin_amdgcn_mfma_f32_16x16x32_bf16(bf, af, acc[nt], 0, 0, 0);
        }
    }

    if (node < N_NODES) {
#pragma unroll
        for (int nt = 0; nt < 8; ++nt) {
            int c0 = nt * 16 + kg * 4;
            float4 bv = *(const float4*)(bias + c0);
            vf4 xv = __builtin_nontemporal_load((const vf4*)(x + (size_t)node * D + c0));
            vf4 o;
            o.x = acc[nt][0] + bv.x + xv.x;
            o.y = acc[nt][1] + bv.y + xv.y;
            o.z = acc[nt][2] + bv.z + xv.z;
            o.w = acc[nt][3] + bv.w + xv.w;
            __builtin_nontemporal_store(o, (vf4*)(out + (size_t)node * D + c0));
        }
    }
}

extern "C" void kernel_launch(void* const* d_in, const int* in_sizes, int n_in,
                              void* d_out, int out_size, void* d_ws, size_t ws_size,
                              hipStream_t stream)
{
    const float* x     = (const float*)d_in[0];
    const void*  ei    = d_in[1];
    const float* gamma = (const float*)d_in[2];
    const float* beta  = (const float*)d_in[3];
    const float* W     = (const float*)d_in[4];
    const float* bias  = (const float*)d_in[5];
    const float* eps_p = (const float*)d_in[6];
    float* out = (float*)d_out;

    char* ws = (char*)d_ws;
    size_t off = 0;
    ushort_t* hb      = (ushort_t*)(ws + off); off += (size_t)N_NODES * D * 2;       // 25.6 MB
    ushort_t* tb      = (ushort_t*)(ws + off); off += (size_t)N_NODES * D * 2;       // 25.6 MB
    int*      bucket  = (int*)(ws + off);      off += (size_t)N_NODES * NSLOT * 4;   // 28.8 MB
    ushort_t* wbf     = (ushort_t*)(ws + off); off += (size_t)D * D * 2;             //  32 KB
    int*      ovf     = (int*)(ws + off);      off += (size_t)OVF_MAX * 2 * 4;       //  32 KB
    int*      ovf_cnt = (int*)(ws + off);      off += 4;

    (void)hipMemsetAsync(bucket, 0, (size_t)N_NODES * NSLOT * 4, stream);  // zero cnts
    (void)hipMemsetAsync(ovf_cnt, 0, 4, stream);
    build_wbf_ln_kernel<<<NB_EDGE + NB_WBF + NB_LN, 256, 0, stream>>>(
        ei, bucket, ovf, ovf_cnt, W, wbf, x, gamma, beta, hb);
    bucket_segsum_kernel<<<N_NODES / 4, 256, 0, stream>>>(
        hb, bucket, ovf, ovf_cnt, eps_p, tb);
    gemm_mfma_kernel<<<(N_NODES + 63) / 64, 256, 0, stream>>>(tb, x, wbf, bias, out);
}

// Round 19
// 226.831 us; speedup vs baseline: 1.3591x; 1.0280x over previous
//
#include <hip/hip_runtime.h>

#define N_NODES 100000
#define N_EDGES 1600000
#define D 128

#define NSLOT   72    // ints per node region (288B, 16B-aligned); [0]=cnt, [4..71]=srcs
#define CAP     68
#define OVF_MAX 4096

typedef unsigned short ushort_t;
struct ushort4_t { ushort_t x, y, z, w; };
typedef __attribute__((ext_vector_type(8))) short bf16x8;
typedef __attribute__((ext_vector_type(4))) float f32x4;
typedef float vf4 __attribute__((ext_vector_type(4)));

#define NB_EDGE (N_EDGES / 256)           // 6250
#define NB_WBF  16
#define NB_LN   (N_NODES / 8)             // 12500

__device__ __forceinline__ ushort_t f2bf(float f) {
    unsigned u = __float_as_uint(f);
    unsigned r = (u + 0x7fffu + ((u >> 16) & 1u)) >> 16;   // RNE
    return (ushort_t)r;
}
__device__ __forceinline__ float bf2f(ushort_t b) {
    return __uint_as_float(((unsigned)b) << 16);
}

// ---------------- K0: zero the inline counters (replaces 28.8MB memset) ----------
__global__ __launch_bounds__(256) void zero_cnt_kernel(
    int* __restrict__ bucket, int* __restrict__ ovf_cnt)
{
    int n = blockIdx.x * 256 + threadIdx.x;
    if (n < N_NODES) bucket[(size_t)n * NSLOT] = 0;
    if (n == 0) *ovf_cnt = 0;
}

// ---------------- K1: bucket scatter (inline cnt) | wbf | LayerNorm+ReLU ---------
// pos = atomicAdd(&bucket[d*72]); dependent src store hits the SAME hot line.
// (r13/r14 config — fastest measured; NT variants regressed.)
__global__ __launch_bounds__(256) void build_wbf_ln_kernel(
    const void* __restrict__ e_raw, int* __restrict__ bucket,
    int* __restrict__ ovf, int* __restrict__ ovf_cnt,
    const float* __restrict__ W, ushort_t* __restrict__ wbf,
    const float* __restrict__ x, const float* __restrict__ gamma,
    const float* __restrict__ beta, ushort_t* __restrict__ hb)
{
    int b = blockIdx.x;
    if (b < NB_EDGE) {
        // inline int64-vs-int32 detect: odd int32 words of first 64 entries all 0
        int li = threadIdx.x & 63;
        int probe = ((const int*)e_raw)[2 * li + 1];
        bool is64 = (__ballot(probe == 0) == ~0ULL);   // wave-uniform

        int e = b * 256 + threadIdx.x;                 // exactly N_EDGES threads
        int s, d;
        if (is64) {
            s = (int)__builtin_nontemporal_load(&((const long long*)e_raw)[e]);
            d = (int)__builtin_nontemporal_load(&((const long long*)e_raw)[N_EDGES + e]);
        } else {
            s = __builtin_nontemporal_load(&((const int*)e_raw)[e]);
            d = __builtin_nontemporal_load(&((const int*)e_raw)[N_EDGES + e]);
        }
        int* reg = bucket + (size_t)d * NSLOT;
        int pos = atomicAdd(reg, 1);
        if (pos < CAP) {
            reg[4 + pos] = s;                          // same hot line as the atomic
        } else {
            int op = atomicAdd(ovf_cnt, 1);            // essentially never
            if (op < OVF_MAX) { ovf[op * 2] = d; ovf[op * 2 + 1] = s; }
        }
    } else if (b < NB_EDGE + NB_WBF) {
        // wbf: W -> bf16, 16 blocks cover 128*128
        int i = ((b - NB_EDGE) * 256 + threadIdx.x) * 4;
        float4 w = *(const float4*)(W + i);
        ushort4_t o;
        o.x = f2bf(w.x); o.y = f2bf(w.y); o.z = f2bf(w.z); o.w = f2bf(w.w);
        *(ushort4_t*)(wbf + i) = o;
    } else {
        int wave   = threadIdx.x >> 6;
        int half   = (threadIdx.x >> 5) & 1;
        int lane32 = threadIdx.x & 31;
        int row = (b - NB_EDGE - NB_WBF) * 8 + wave * 2 + half;
        float4 v = ((const float4*)(x + (size_t)row * D))[lane32];
        float s  = (v.x + v.y) + (v.z + v.w);
        float sq = (v.x * v.x + v.y * v.y) + (v.z * v.z + v.w * v.w);
#pragma unroll
        for (int m = 16; m >= 1; m >>= 1) {
            s  += __shfl_xor(s, m);
            sq += __shfl_xor(sq, m);
        }
        float mu   = s * (1.0f / D);
        float var  = sq * (1.0f / D) - mu * mu;
        float rstd = rsqrtf(var + 1e-5f);
        float4 g = ((const float4*)gamma)[lane32];
        float4 bb = ((const float4*)beta)[lane32];
        ushort4_t o;
        o.x = f2bf(fmaxf(fmaf((v.x - mu) * rstd, g.x, bb.x), 0.0f));
        o.y = f2bf(fmaxf(fmaf((v.y - mu) * rstd, g.y, bb.y), 0.0f));
        o.z = f2bf(fmaxf(fmaf((v.z - mu) * rstd, g.z, bb.z), 0.0f));
        o.w = f2bf(fmaxf(fmaf((v.w - mu) * rstd, g.w, bb.w), 0.0f));
        *(ushort4_t*)(hb + (size_t)row * D + lane32 * 4) = o;
    }
}

// ---------------- K2: bucket segment sum + t-fold — TWO nodes per wave -----------
// 16 independent row-gathers in flight per wave (2 nodes x 8-chunk interleave).
// Emits t = bf16(ep1*h[n] + sum(h[src])) — the GEMM A-operand.
__global__ __launch_bounds__(256) void bucket_segsum_kernel(
    const ushort_t* __restrict__ hb, const int* __restrict__ bucket,
    const int* __restrict__ ovf, const int* __restrict__ ovf_cnt,
    const float* __restrict__ eps_p, ushort_t* __restrict__ tb)
{
    int wid  = blockIdx.x * 4 + (threadIdx.x >> 6);
    int lane = threadIdx.x & 63;
    int n0 = wid * 2;
    int n1 = n0 + 1;
    const int* reg0 = bucket + (size_t)n0 * NSLOT;
    const int* reg1 = bucket + (size_t)n1 * NSLOT;
    int deg0 = reg0[0];
    int deg1 = reg1[0];
    int end0 = deg0 < CAP ? deg0 : CAP;
    int end1 = deg1 < CAP ? deg1 : CAP;
    const int* seg0 = reg0 + 4;
    const int* seg1 = reg1 + 4;
    const unsigned* hrow = (const unsigned*)hb;   // 64 dwords per node row
    float a0x = 0.0f, a0y = 0.0f, a1x = 0.0f, a1y = 0.0f;
    int e0 = 0, e1 = 0;

    while (e0 + 8 <= end0 || e1 + 8 <= end1) {
        bool t0 = (e0 + 8 <= end0);
        bool t1 = (e1 + 8 <= end1);
        if (t0) {
            int4 sa = *(const int4*)(seg0 + e0);
            int4 sb = *(const int4*)(seg0 + e0 + 4);
            unsigned p0 = hrow[(size_t)sa.x * 64 + lane];
            unsigned p1 = hrow[(size_t)sa.y * 64 + lane];
            unsigned p2 = hrow[(size_t)sa.z * 64 + lane];
            unsigned p3 = hrow[(size_t)sa.w * 64 + lane];
            unsigned p4 = hrow[(size_t)sb.x * 64 + lane];
            unsigned p5 = hrow[(size_t)sb.y * 64 + lane];
            unsigned p6 = hrow[(size_t)sb.z * 64 + lane];
            unsigned p7 = hrow[(size_t)sb.w * 64 + lane];
            a0x += bf2f((ushort_t)(p0 & 0xffffu)) + bf2f((ushort_t)(p1 & 0xffffu))
                 + bf2f((ushort_t)(p2 & 0xffffu)) + bf2f((ushort_t)(p3 & 0xffffu))
                 + bf2f((ushort_t)(p4 & 0xffffu)) + bf2f((ushort_t)(p5 & 0xffffu))
                 + bf2f((ushort_t)(p6 & 0xffffu)) + bf2f((ushort_t)(p7 & 0xffffu));
            a0y += bf2f((ushort_t)(p0 >> 16)) + bf2f((ushort_t)(p1 >> 16))
                 + bf2f((ushort_t)(p2 >> 16)) + bf2f((ushort_t)(p3 >> 16))
                 + bf2f((ushort_t)(p4 >> 16)) + bf2f((ushort_t)(p5 >> 16))
                 + bf2f((ushort_t)(p6 >> 16)) + bf2f((ushort_t)(p7 >> 16));
            e0 += 8;
        }
        if (t1) {
            int4 sa = *(const int4*)(seg1 + e1);
            int4 sb = *(const int4*)(seg1 + e1 + 4);
            unsigned q0 = hrow[(size_t)sa.x * 64 + lane];
            unsigned q1 = hrow[(size_t)sa.y * 64 + lane];
            unsigned q2 = hrow[(size_t)sa.z * 64 + lane];
            unsigned q3 = hrow[(size_t)sa.w * 64 + lane];
            unsigned q4 = hrow[(size_t)sb.x * 64 + lane];
            unsigned q5 = hrow[(size_t)sb.y * 64 + lane];
            unsigned q6 = hrow[(size_t)sb.z * 64 + lane];
            unsigned q7 = hrow[(size_t)sb.w * 64 + lane];
            a1x += bf2f((ushort_t)(q0 & 0xffffu)) + bf2f((ushort_t)(q1 & 0xffffu))
                 + bf2f((ushort_t)(q2 & 0xffffu)) + bf2f((ushort_t)(q3 & 0xffffu))
                 + bf2f((ushort_t)(q4 & 0xffffu)) + bf2f((ushort_t)(q5 & 0xffffu))
                 + bf2f((ushort_t)(q6 & 0xffffu)) + bf2f((ushort_t)(q7 & 0xffffu));
            a1y += bf2f((ushort_t)(q0 >> 16)) + bf2f((ushort_t)(q1 >> 16))
                 + bf2f((ushort_t)(q2 >> 16)) + bf2f((ushort_t)(q3 >> 16))
                 + bf2f((ushort_t)(q4 >> 16)) + bf2f((ushort_t)(q5 >> 16))
                 + bf2f((ushort_t)(q6 >> 16)) + bf2f((ushort_t)(q7 >> 16));
            e1 += 8;
        }
    }
    for (; e0 < end0; ++e0) {
        unsigned p = hrow[(size_t)seg0[e0] * 64 + lane];
        a0x += bf2f((ushort_t)(p & 0xffffu));
        a0y += bf2f((ushort_t)(p >> 16));
    }
    for (; e1 < end1; ++e1) {
        unsigned p = hrow[(size_t)seg1[e1] * 64 + lane];
        a1x += bf2f((ushort_t)(p & 0xffffu));
        a1y += bf2f((ushort_t)(p >> 16));
    }

    // overflow entries (count ~0; wave-uniform branch)
    int oc = *ovf_cnt;
    if (oc > 0) {
        oc = oc < OVF_MAX ? oc : OVF_MAX;
        for (int i = 0; i < oc; ++i) {
            int dn = ovf[2 * i];
            if (dn == n0 || dn == n1) {
                unsigned p = hrow[(size_t)ovf[2 * i + 1] * 64 + lane];
                if (dn == n0) { a0x += bf2f((ushort_t)(p & 0xffffu)); a0y += bf2f((ushort_t)(p >> 16)); }
                else          { a1x += bf2f((ushort_t)(p & 0xffffu)); a1y += bf2f((ushort_t)(p >> 16)); }
            }
        }
    }

    // fold own h rows: t = ep1*h + aggr
    float ep1 = 1.0f + eps_p[0];
    unsigned hp0 = hrow[(size_t)n0 * 64 + lane];
    unsigned hp1 = hrow[(size_t)n1 * 64 + lane];
    a0x = fmaf(ep1, bf2f((ushort_t)(hp0 & 0xffffu)), a0x);
    a0y = fmaf(ep1, bf2f((ushort_t)(hp0 >> 16)), a0y);
    a1x = fmaf(ep1, bf2f((ushort_t)(hp1 & 0xffffu)), a1x);
    a1y = fmaf(ep1, bf2f((ushort_t)(hp1 >> 16)), a1y);

    __builtin_nontemporal_store((unsigned)f2bf(a0x) | ((unsigned)f2bf(a0y) << 16),
                                (unsigned*)tb + (size_t)n0 * 64 + lane);
    __builtin_nontemporal_store((unsigned)f2bf(a1x) | ((unsigned)f2bf(a1y) << 16),
                                (unsigned*)tb + (size_t)n1 * 64 + lane);
}

// ---------------- K3: out = t @ W^T + b + x  (MFMA, swapped operands) ------------
__global__ __launch_bounds__(256) void gemm_mfma_kernel(
    const ushort_t* __restrict__ tb, const float* __restrict__ x,
    const ushort_t* __restrict__ wbf, const float* __restrict__ bias,
    float* __restrict__ out)
{
    const int wv   = threadIdx.x >> 6;
    const int lane = threadIdx.x & 63;
    const int l16  = lane & 15;
    const int kg   = lane >> 4;                 // 0..3
    const int node = blockIdx.x * 64 + wv * 16 + l16;
    const int rowc = node < N_NODES ? node : N_NODES - 1;

    f32x4 acc[8];
#pragma unroll
    for (int nt = 0; nt < 8; ++nt) acc[nt] = (f32x4){0.f, 0.f, 0.f, 0.f};

#pragma unroll
    for (int ks = 0; ks < 4; ++ks) {
        const int k0 = ks * 32 + kg * 8;
        bf16x8 af = *(const bf16x8*)(tb + (size_t)rowc * D + k0);
#pragma unroll
        for (int nt = 0; nt < 8; ++nt) {
            bf16x8 bf = *(const bf16x8*)(wbf + (size_t)(nt * 16 + l16) * D + k0);
            acc[nt] = __builtin_amdgcn_mfma_f32_16x16x32_bf16(bf, af, acc[nt], 0, 0, 0);
        }
    }

    if (node < N_NODES) {
#pragma unroll
        for (int nt = 0; nt < 8; ++nt) {
            int c0 = nt * 16 + kg * 4;
            float4 bv = *(const float4*)(bias + c0);
            vf4 xv = __builtin_nontemporal_load((const vf4*)(x + (size_t)node * D + c0));
            vf4 o;
            o.x = acc[nt][0] + bv.x + xv.x;
            o.y = acc[nt][1] + bv.y + xv.y;
            o.z = acc[nt][2] + bv.z + xv.z;
            o.w = acc[nt][3] + bv.w + xv.w;
            __builtin_nontemporal_store(o, (vf4*)(out + (size_t)node * D + c0));
        }
    }
}

extern "C" void kernel_launch(void* const* d_in, const int* in_sizes, int n_in,
                              void* d_out, int out_size, void* d_ws, size_t ws_size,
                              hipStream_t stream)
{
    const float* x     = (const float*)d_in[0];
    const void*  ei    = d_in[1];
    const float* gamma = (const float*)d_in[2];
    const float* beta  = (const float*)d_in[3];
    const float* W     = (const float*)d_in[4];
    const float* bias  = (const float*)d_in[5];
    const float* eps_p = (const float*)d_in[6];
    float* out = (float*)d_out;

    char* ws = (char*)d_ws;
    size_t off = 0;
    ushort_t* hb      = (ushort_t*)(ws + off); off += (size_t)N_NODES * D * 2;       // 25.6 MB
    ushort_t* tb      = (ushort_t*)(ws + off); off += (size_t)N_NODES * D * 2;       // 25.6 MB
    int*      bucket  = (int*)(ws + off);      off += (size_t)N_NODES * NSLOT * 4;   // 28.8 MB
    ushort_t* wbf     = (ushort_t*)(ws + off); off += (size_t)D * D * 2;             //  32 KB
    int*      ovf     = (int*)(ws + off);      off += (size_t)OVF_MAX * 2 * 4;       //  32 KB
    int*      ovf_cnt = (int*)(ws + off);      off += 4;

    zero_cnt_kernel<<<(N_NODES + 255) / 256, 256, 0, stream>>>(bucket, ovf_cnt);
    build_wbf_ln_kernel<<<NB_EDGE + NB_WBF + NB_LN, 256, 0, stream>>>(
        ei, bucket, ovf, ovf_cnt, W, wbf, x, gamma, beta, hb);
    bucket_segsum_kernel<<<N_NODES / 8, 256, 0, stream>>>(
        hb, bucket, ovf, ovf_cnt, eps_p, tb);
    gemm_mfma_kernel<<<(N_NODES + 63) / 64, 256, 0, stream>>>(tb, x, wbf, bias, out);
}